// Round 1
// baseline (820.027 us; speedup 1.0000x reference)
//
#include <hip/hip_runtime.h>
#include <math.h>

#define B_ 16
#define NSUP_ 4096
#define NQ_ 4096
#define D_ 512
#define C_ 128
#define DCH 64

// ---------------- kernel 1: prototypes ----------------
// grid: B_ * (C_/8) = 256 blocks, 256 threads
// Each block handles batch b and 8 classes; thread t owns dims (t, t+256).
__global__ __launch_bounds__(256) void proto_kernel(
    const float* __restrict__ sup, const int* __restrict__ tgt,
    float* __restrict__ protos,   // [B_][C_][D_] f32
    double* __restrict__ p_sq)    // [B_][C_]   f64 (of the f32 protos)
{
    __shared__ int    lt[NSUP_];        // 16 KB
    __shared__ double acc[8][D_];       // 32 KB
    __shared__ double redbuf[256];      // 2 KB
    __shared__ int    cnts[8];

    int blk = blockIdx.x;
    int b   = blk >> 4;
    int cg  = (blk & 15) * 8;
    int tid = threadIdx.x;
    int d0 = tid, d1 = tid + 256;

    for (int i = tid; i < NSUP_; i += 256) lt[i] = tgt[b*NSUP_ + i];
    for (int k = 0; k < 8; k++) { acc[k][d0] = 0.0; acc[k][d1] = 0.0; }
    __syncthreads();

    const float* e = sup + (size_t)b*NSUP_*D_;
    int mycnt = 0;  // thread k<8 counts class cg+k
    for (int n = 0; n < NSUP_; n++) {
        int idx = lt[n] - cg;
        if ((unsigned)idx < 8u) {
            acc[idx][d0] += (double)e[(size_t)n*D_ + d0];
            acc[idx][d1] += (double)e[(size_t)n*D_ + d1];
            if (tid == idx) mycnt++;
        }
    }
    __syncthreads();
    if (tid < 8) cnts[tid] = mycnt;
    __syncthreads();

    for (int k = 0; k < 8; k++) {
        double cw = (double)(cnts[k] > 1 ? cnts[k] : 1);
        double p0 = acc[k][d0] / cw;
        double p1 = acc[k][d1] / cw;
        float f0 = (float)p0, f1 = (float)p1;
        size_t base = ((size_t)(b*C_ + cg + k))*D_;
        protos[base + d0] = f0;
        protos[base + d1] = f1;
        redbuf[tid] = (double)f0*(double)f0 + (double)f1*(double)f1;
        __syncthreads();
        for (int s = 128; s > 0; s >>= 1) {
            if (tid < s) redbuf[tid] += redbuf[tid + s];
            __syncthreads();
        }
        if (tid == 0) p_sq[b*C_ + cg + k] = redbuf[0];
        __syncthreads();
    }
}

// ---------------- kernel 2: fused distances + argmin + lse + nll ----------------
// grid: B_ * (NQ_/32) = 2048 blocks, 256 threads (4 waves, 8 queries/wave).
// Lane l owns classes l and l+64. f64 accumulation for exact argmin.
__global__ __launch_bounds__(256) void dist_kernel(
    const float* __restrict__ qry, const int* __restrict__ qtgt,
    const float* __restrict__ protos, const double* __restrict__ p_sq,
    float* __restrict__ out_pred, double* __restrict__ blk_loss,
    float* __restrict__ blk_acc)
{
    __shared__ float ldsPT[DCH][C_ + 1];  // protos^T chunk, +1 pad: 33,024 B
    __shared__ float ldsQ[4][8][DCH];     // per-wave query chunk: 8,192 B
    __shared__ double wl[4];
    __shared__ float  wa[4];

    int blk  = blockIdx.x;
    int b    = blk >> 7;            // 128 blocks per batch
    int qb   = (blk & 127) * 32;
    int tid  = threadIdx.x;
    int wave = tid >> 6, lane = tid & 63;
    int q0   = qb + wave * 8;

    const float* qbase = qry + ((size_t)b*NQ_ + q0)*D_;

    // per-query ||q||^2 in f64
    double qsq[8];
    for (int j = 0; j < 8; j++) {
        const float* qp = qbase + (size_t)j*D_;
        double ss = 0.0;
        #pragma unroll
        for (int k = 0; k < 8; k++) {
            double v = (double)qp[lane + 64*k];
            ss = fma(v, v, ss);
        }
        for (int off = 32; off; off >>= 1) ss += __shfl_xor(ss, off, 64);
        qsq[j] = ss;
    }

    double acc0[8] = {0,0,0,0,0,0,0,0};   // class = lane
    double acc1[8] = {0,0,0,0,0,0,0,0};   // class = lane + 64

    const float* pb = protos + (size_t)b*C_*D_;

    for (int ch = 0; ch < D_/DCH; ch++) {
        __syncthreads();
        // stage protos^T: (c, dl) -> ldsPT[dl][c]; coalesced global reads
        for (int i = tid; i < C_*DCH; i += 256) {
            int c = i >> 6, dl = i & 63;
            ldsPT[dl][c] = pb[(size_t)c*D_ + ch*DCH + dl];
        }
        // stage this wave's 8 queries for this d-chunk
        #pragma unroll
        for (int j = 0; j < 8; j++)
            ldsQ[wave][j][lane] = qbase[(size_t)j*D_ + ch*DCH + lane];
        __syncthreads();

        #pragma unroll 4
        for (int dl = 0; dl < DCH; dl++) {
            double p0 = (double)ldsPT[dl][lane];
            double p1 = (double)ldsPT[dl][lane + 64];
            #pragma unroll
            for (int j = 0; j < 8; j++) {
                double qv = (double)ldsQ[wave][j][dl];
                acc0[j] = fma(p0, qv, acc0[j]);
                acc1[j] = fma(p1, qv, acc1[j]);
            }
        }
    }
    __syncthreads();

    double ps0 = p_sq[b*C_ + lane];
    double ps1 = p_sq[b*C_ + lane + 64];

    double wloss = 0.0; float waccv = 0.0f;

    for (int j = 0; j < 8; j++) {
        double dl0 = ps0 + qsq[j] - 2.0*acc0[j];
        double dl1 = ps1 + qsq[j] - 2.0*acc1[j];

        // local argmin (strict <: smaller class index wins ties; lane < lane+64)
        double bd; int bc;
        if (dl1 < dl0) { bd = dl1; bc = lane + 64; } else { bd = dl0; bc = lane; }
        // butterfly argmin across wave; exact-tie -> smaller class index
        for (int off = 32; off; off >>= 1) {
            double od = __shfl_xor(bd, off, 64);
            int    oc = __shfl_xor(bc, off, 64);
            if (od < bd || (od == bd && oc < bc)) { bd = od; bc = oc; }
        }

        // logsumexp of (-dist) over 128 classes
        float nd0 = (float)(-dl0), nd1 = (float)(-dl1);
        float lm = fmaxf(nd0, nd1);
        float ls = __expf(nd0 - lm) + __expf(nd1 - lm);
        for (int off = 32; off; off >>= 1) {
            float om = __shfl_xor(lm, off, 64);
            float os = __shfl_xor(ls, off, 64);
            float nm = fmaxf(lm, om);
            ls = ls * __expf(lm - nm) + os * __expf(om - nm);
            lm = nm;
        }

        int tq = qtgt[b*NQ_ + q0 + j];
        double cand = (tq & 64) ? dl1 : dl0;
        double dt = __shfl(cand, tq & 63, 64);
        double nll = dt + (double)lm + (double)logf(ls);

        if (lane == 0) out_pred[(size_t)b*NQ_ + q0 + j] = (float)bc;
        wloss += nll;
        waccv += (bc == tq) ? 1.0f : 0.0f;
    }

    if (lane == 0) { wl[wave] = wloss; wa[wave] = waccv; }
    __syncthreads();
    if (tid == 0) {
        blk_loss[blk] = wl[0] + wl[1] + wl[2] + wl[3];
        blk_acc[blk]  = wa[0] + wa[1] + wa[2] + wa[3];
    }
}

// ---------------- kernel 3: finalize loss + accuracy ----------------
__global__ __launch_bounds__(256) void finalize_kernel(
    const double* __restrict__ blk_loss, const float* __restrict__ blk_acc,
    float* __restrict__ out)
{
    __shared__ double rl[256];
    __shared__ float  ra[256];
    int tid = threadIdx.x;
    double s = 0.0; float a = 0.0f;
    for (int i = tid; i < 2048; i += 256) { s += blk_loss[i]; a += blk_acc[i]; }
    rl[tid] = s; ra[tid] = a;
    __syncthreads();
    for (int st = 128; st; st >>= 1) {
        if (tid < st) { rl[tid] += rl[tid + st]; ra[tid] += ra[tid + st]; }
        __syncthreads();
    }
    if (tid == 0) {
        out[B_*NQ_    ] = (float)(rl[0] / (double)(B_*NQ_));
        out[B_*NQ_ + 1] = ra[0] / (float)(B_*NQ_);
    }
}

extern "C" void kernel_launch(void* const* d_in, const int* in_sizes, int n_in,
                              void* d_out, int out_size, void* d_ws, size_t ws_size,
                              hipStream_t stream) {
    const float* sup  = (const float*)d_in[0];
    const float* qry  = (const float*)d_in[1];
    const int*   stgt = (const int*)d_in[2];
    const int*   qtgt = (const int*)d_in[3];
    float* out = (float*)d_out;

    char* ws = (char*)d_ws;
    float*  protos   = (float*) (ws);                               // 4 MiB
    double* p_sq     = (double*)(ws + 4*1024*1024);                 // 16 KiB
    double* blk_loss = (double*)(ws + 4*1024*1024 + 16*1024);       // 16 KiB
    float*  blk_acc  = (float*) (ws + 4*1024*1024 + 32*1024);       // 8 KiB

    hipLaunchKernelGGL(proto_kernel, dim3(256), dim3(256), 0, stream,
                       sup, stgt, protos, p_sq);
    hipLaunchKernelGGL(dist_kernel, dim3(2048), dim3(256), 0, stream,
                       qry, qtgt, protos, p_sq, out, blk_loss, blk_acc);
    hipLaunchKernelGGL(finalize_kernel, dim3(1), dim3(256), 0, stream,
                       blk_loss, blk_acc, out);
}